// Round 6
// baseline (384.005 us; speedup 1.0000x reference)
//
#include <hip/hip_runtime.h>
#include <stdint.h>

// ============================================================================
// JAX threefry2x32 PRNG reproduction (partitionable semantics, verified R0).
// ============================================================================
struct U2 { unsigned a, b; };

__device__ __forceinline__ unsigned rotl32(unsigned v, int r) {
  return (v << r) | (v >> (32 - r));
}

__device__ __forceinline__ U2 tf(U2 k, unsigned x0, unsigned x1) {
  unsigned ks0 = k.a, ks1 = k.b, ks2 = k.a ^ k.b ^ 0x1BD11BDAu;
  x0 += ks0; x1 += ks1;
#define TFG(RA, RB, RC, RD, KA, KB, INC)                  \
  x0 += x1; x1 = rotl32(x1, RA); x1 ^= x0;                \
  x0 += x1; x1 = rotl32(x1, RB); x1 ^= x0;                \
  x0 += x1; x1 = rotl32(x1, RC); x1 ^= x0;                \
  x0 += x1; x1 = rotl32(x1, RD); x1 ^= x0;                \
  x0 += KA; x1 += KB + INC;
  TFG(13, 15, 26, 6, ks1, ks2, 1u)
  TFG(17, 29, 16, 24, ks2, ks0, 2u)
  TFG(13, 15, 26, 6, ks0, ks1, 3u)
  TFG(17, 29, 16, 24, ks1, ks2, 4u)
  TFG(13, 15, 26, 6, ks2, ks0, 5u)
#undef TFG
  U2 r; r.a = x0; r.b = x1; return r;
}

__device__ __forceinline__ U2 split_key(U2 key, int num, int j) {
  (void)num;
  return tf(key, 0u, (unsigned)j);
}
__device__ __forceinline__ unsigned random_bits(U2 key, int n, unsigned e) {
  (void)n;
  U2 r = tf(key, 0u, e);
  return r.a ^ r.b;
}

__device__ __forceinline__ U2 root_key() { U2 k; k.a = 0u; k.b = 42u; return k; }

__device__ __forceinline__ float jax_uniform(U2 key, int n, unsigned e,
                                             float minv, float maxv) {
  unsigned b = random_bits(key, n, e);
  float u = __uint_as_float((b >> 9) | 0x3f800000u) - 1.0f;
  float r = u * (maxv - minv) + minv;
  return fmaxf(minv, r);
}

#define ROTR 0.7853981633974483f
#define SENTINEL 0xFFFFFFFFu  // -NaN bit pattern; unreachable for all
                              // published values (clamped floats / positive
                              // fitness; arithmetic NaNs are 0x7FC00000)

// packed fp32 pair (lowered to v_pk_* VOP3P on gfx90a+/gfx950)
typedef float f2 __attribute__((ext_vector_type(2)));
__device__ __forceinline__ f2 sp2(float s) { f2 v; v.x = s; v.y = s; return v; }
__device__ __forceinline__ f2 fma2(f2 a, f2 b, f2 c) {
  return __builtin_elementwise_fma(a, b, c);
}
__device__ __forceinline__ f2 max2(f2 a, f2 b) {
  return __builtin_elementwise_max(a, b);
}

__device__ __forceinline__ void compute_R(float vx, float vy, float vz,
                                          float R[3][3]) {
  float nsq = vx * vx + vy * vy + vz * vz;
  float theta = sqrtf(nsq);
  if (theta < 1e-8f) {
    R[0][0] = 1.f; R[0][1] = 0.f; R[0][2] = 0.f;
    R[1][0] = 0.f; R[1][1] = 1.f; R[1][2] = 0.f;
    R[2][0] = 0.f; R[2][1] = 0.f; R[2][2] = 1.f;
    return;
  }
  float m = fmaxf(theta, 1e-8f);
  float kx = vx / m, ky = vy / m, kz = vz / m;
  float s = sinf(theta), c = cosf(theta);
  float K[3][3] = {{0.f, -kz, ky}, {kz, 0.f, -kx}, {-ky, kx, 0.f}};
  float K2[3][3];
#pragma unroll
  for (int i = 0; i < 3; i++)
#pragma unroll
    for (int j = 0; j < 3; j++)
      K2[i][j] = fmaf(K[i][2], K[2][j], fmaf(K[i][1], K[1][j], K[i][0] * K[0][j]));
  float omc = 1.0f - c;
#pragma unroll
  for (int i = 0; i < 3; i++)
#pragma unroll
    for (int j = 0; j < 3; j++)
      R[i][j] = ((i == j) ? 1.0f : 0.0f) + s * K[i][j] + omc * K2[i][j];
}

// composite sort key for stream s (0:src r1, 1:src r2, 2:tgt r1, 3:tgt r2)
__device__ __forceinline__ unsigned long long make_composite(int s, int i) {
  U2 root = root_key();
  U2 kp = split_key(root, 5, s >> 1);
  U2 key;
  if ((s & 1) == 0) {
    key = split_key(kp, 2, 1);
  } else {
    U2 kA = split_key(kp, 2, 0);
    key = split_key(kA, 2, 1);
  }
  unsigned rb = random_bits(key, 16384, (unsigned)i);
  return ((unsigned long long)rb << 32) | (unsigned)i;
}

// ============================================================================
// Agent-scope RELAXED access helpers — bypass non-coherent L1/L2, hit LLC.
// NO acquire/release fences anywhere (R3 lesson: agent fences emit
// buffer_inv/buffer_wbl2 walks; 96K of them serialized all memory traffic).
// Ordering model (R5): write-once word-granular sentinel publication —
// a word is valid iff != SENTINEL; no cross-word ordering ever needed.
// ============================================================================
__device__ __forceinline__ float gload(const float* p) {
  return __hip_atomic_load(const_cast<float*>(p), __ATOMIC_RELAXED,
                           __HIP_MEMORY_SCOPE_AGENT);
}
__device__ __forceinline__ void gstore(float* p, float v) {
  __hip_atomic_store(p, v, __ATOMIC_RELAXED, __HIP_MEMORY_SCOPE_AGENT);
}
__device__ __forceinline__ unsigned uload(const unsigned* p) {
  return __hip_atomic_load(const_cast<unsigned*>(p), __ATOMIC_RELAXED,
                           __HIP_MEMORY_SCOPE_AGENT);
}

// poll a published word until it is valid (write-once, sentinel-initialized);
// s_sleep in the retry path keeps spin waves off the VALU issue ports (R6).
__device__ __forceinline__ float poll_word(const float* p) {
  const unsigned* up = (const unsigned*)p;
  unsigned v = uload(up);
  while (v == SENTINEL) {
    __builtin_amdgcn_s_sleep(1);
    v = uload(up);
  }
  return __uint_as_float(v);
}

// ============================================================================
// Bucket-sort rank pipeline (verified R3-R6/R10) — WIDE dispatches.
// ============================================================================
__global__ __launch_bounds__(256) void hist_kernel(unsigned* __restrict__ hist) {
  int gid = blockIdx.x * 256 + threadIdx.x;  // 65536
  int s = gid >> 14, i = gid & 16383;
  unsigned long long c = make_composite(s, i);
  unsigned bucket = (unsigned)(c >> 56);
  atomicAdd(&hist[s * 256 + bucket], 1u);
}

__global__ __launch_bounds__(256) void prefix_kernel(
    const unsigned* __restrict__ hist, unsigned* __restrict__ base,
    unsigned* __restrict__ cursor) {
  __shared__ unsigned h[4][256];
  int t = threadIdx.x;
#pragma unroll
  for (int s = 0; s < 4; s++) h[s][t] = hist[s * 256 + t];
  __syncthreads();
#pragma unroll
  for (int s = 0; s < 4; s++) {
    unsigned acc = 0;
    for (int j = 0; j < 256; j++) acc += (j < t) ? h[s][j] : 0u;
    base[s * 256 + t] = acc;
    cursor[s * 256 + t] = acc;
  }
}

__global__ __launch_bounds__(256) void scatterb_kernel(
    unsigned* __restrict__ cursor, unsigned long long* __restrict__ sorted) {
  int gid = blockIdx.x * 256 + threadIdx.x;  // 65536
  int s = gid >> 14, i = gid & 16383;
  unsigned long long c = make_composite(s, i);
  unsigned bucket = (unsigned)(c >> 56);
  unsigned pos = atomicAdd(&cursor[s * 256 + bucket], 1u);
  sorted[(s << 14) + pos] = c;
}

__global__ __launch_bounds__(256) void rank_kernel(
    const unsigned long long* __restrict__ sorted,
    const unsigned* __restrict__ base, const unsigned* __restrict__ hist,
    unsigned* __restrict__ rank_all, unsigned* __restrict__ x1buf) {
  int gid = blockIdx.x * 256 + threadIdx.x;  // 65536
  int s = gid >> 14, k = gid & 16383;
  unsigned long long c = sorted[(s << 14) + k];
  unsigned bucket = (unsigned)(c >> 56);
  unsigned b0 = base[s * 256 + bucket];
  unsigned cnt = hist[s * 256 + bucket];
  unsigned less = 0;
  for (unsigned j = 0; j < cnt; j++)
    less += (sorted[(s << 14) + b0 + j] < c) ? 1u : 0u;
  unsigned i = (unsigned)(c & 0xffffffffull);
  unsigned rank = b0 + less;
  if ((s & 1) == 0) x1buf[((s >> 1) << 14) + rank] = i;
  else              rank_all[(s << 14) + i] = rank;
}

__global__ __launch_bounds__(256) void idx_kernel(
    const unsigned* __restrict__ rank_all, const unsigned* __restrict__ x1buf,
    int* __restrict__ idx) {
  int gid = blockIdx.x * 256 + threadIdx.x;  // 32768
  int perm = gid >> 14, i = gid & 16383;
  unsigned r = rank_all[((perm * 2 + 1) << 14) + i];
  if (r < 128u) idx[perm * 128 + (int)r] = (int)x1buf[(perm << 14) + i];
}

// ============================================================================
// setup (blocks 0..31) + DE-schedule precompute (blocks 32..991).
// Also sentinel-initializes estate (folds away the hipMemsetAsync dispatch;
// kernel-end L2 writeback makes these normal stores visible to de_loop's
// LLC-direct atomic polls).
// ============================================================================
__global__ __launch_bounds__(128) void setupperm_kernel(
    const float* __restrict__ source, const float* __restrict__ target,
    const int* __restrict__ idx, float* __restrict__ src,
    float* __restrict__ tgt, float* __restrict__ yn,
    unsigned* __restrict__ packg, unsigned* __restrict__ ewords) {
  int blk = blockIdx.x;
  int tid = threadIdx.x;
  // sentinel-init estate: 384000 words over 992*128 = 126976 threads
  for (int i = blk * 128 + tid; i < 384000; i += 126976)
    ewords[i] = SENTINEL;
  if (blk < 32) {
    int b = blk;
    int is = idx[tid], it = idx[128 + tid];
#pragma unroll
    for (int d = 0; d < 3; d++)
      src[(b * 128 + tid) * 3 + d] = source[((size_t)b * 16384 + is) * 3 + d];
    float y0 = target[((size_t)b * 16384 + it) * 3 + 0];
    float y1 = target[((size_t)b * 16384 + it) * 3 + 1];
    float y2 = target[((size_t)b * 16384 + it) * 3 + 2];
    tgt[(b * 128 + tid) * 3 + 0] = y0;
    tgt[(b * 128 + tid) * 3 + 1] = y1;
    tgt[(b * 128 + tid) * 3 + 2] = y2;
    yn[b * 128 + tid] = y0 * y0 + y1 * y1 + y2 * y2;
    return;
  }
  int blk2 = blk - 32;  // 960
  int it = blk2 >> 5, b = blk2 & 31;
  __shared__ unsigned pbits[3][64];
  __shared__ int lperm[3][64];
  U2 root = root_key();
  U2 kloop = split_key(root, 5, 4);
  U2 kit = split_key(kloop, 30, it);
  U2 ka = split_key(kit, 3, 0);
  for (int e = tid; e < 150; e += 128) {
    int r = e / 50, q = e % 50;
    U2 pk = split_key(ka, 96, r * 32 + b);
    U2 sub = split_key(pk, 2, 1);
    pbits[r][q] = random_bits(sub, 50, (unsigned)q);
  }
  __syncthreads();
  for (int e = tid; e < 150; e += 128) {
    int r = e / 50, q = e % 50;
    unsigned bq = pbits[r][q];
    int cnt = 0;
    for (int j = 0; j < 50; j++) {
      unsigned bj = pbits[r][j];
      cnt += (bj < bq || (bj == bq && j < q)) ? 1 : 0;
    }
    lperm[r][cnt] = q;
  }
  __syncthreads();
  if (tid < 50) {
    int p = tid, bp = b * 50 + p;
    U2 kb = split_key(kit, 3, 1);
    U2 kc = split_key(kit, 3, 2);
    U2 kc1 = split_key(kc, 2, 0), kc2 = split_key(kc, 2, 1);
    unsigned hb = random_bits(kc1, 1600, (unsigned)bp);
    unsigned lb = random_bits(kc2, 1600, (unsigned)bp);
    int jr = (int)((((hb % 6u) * 4u) + (lb % 6u)) % 6u);
    unsigned mask = 0;
#pragma unroll
    for (int d = 0; d < 6; d++) {
      unsigned rb = random_bits(kb, 9600, (unsigned)(bp * 6 + d));
      float u = __uint_as_float((rb >> 9) | 0x3f800000u) - 1.0f;
      if ((u < 0.9f) || (d == jr)) mask |= (1u << d);
    }
    unsigned pack = (unsigned)lperm[0][p] | ((unsigned)lperm[1][p] << 6) |
                    ((unsigned)lperm[2][p] << 12) | (mask << 18);
    packg[(it * 32 + b) * 50 + p] = pack;
  }
}

// ============================================================================
// Chamfer eval core — packed-fp32 (R6). Per 2-column pair: dot/d2 arithmetic
// in f2 (v_pk_fma/add/mul); min/max chain scalar (no pk_min_f32 on CDNA).
// Numerics are element-identical to the verified scalar path: same fma/add/
// mul sequences per column, racc min visits columns in the same ascending
// order, cacc per-column expressions unchanged.
// LDS layout syp: per cq-group of 32 cols, 16 pairs x 2 float4:
//   syp[(cq<<5)+2*jj+0] = {yx0, yx1, yy0, yy1}
//   syp[(cq<<5)+2*jj+1] = {yz0, yz1, yw0, yw1}
// ============================================================================
__device__ __forceinline__ float eval_pose_core(
    float p0, float p1, float p2, float p3, float p4, float p5,
    float s0, float s1, float s2, int tid, const float4* syp, float4* xsv,
    float* rowpart, float* red1, float* red2) {
  float Rm[3][3];
  compute_R(p0, p1, p2, Rm);
  float x0 = fmaf(Rm[0][2], s2, fmaf(Rm[0][1], s1, Rm[0][0] * s0)) + p3;
  float x1 = fmaf(Rm[1][2], s2, fmaf(Rm[1][1], s1, Rm[1][0] * s0)) + p4;
  float x2 = fmaf(Rm[2][2], s2, fmaf(Rm[2][1], s1, Rm[2][0] * s0)) + p5;
  float xn = x0 * x0 + x1 * x1 + x2 * x2;
  xsv[tid] = make_float4(x0, x1, x2, xn);
  __syncthreads();
  int rg = tid & 31, cq = tid >> 5;
  float4 xr0 = xsv[4 * rg + 0];
  float4 xr1 = xsv[4 * rg + 1];
  float4 xr2 = xsv[4 * rg + 2];
  float4 xr3 = xsv[4 * rg + 3];
  float racc0 = 3.402823466e38f, racc1 = 3.402823466e38f;
  float racc2 = 3.402823466e38f, racc3 = 3.402823466e38f;
  float cacc[32];
#pragma unroll
  for (int jj = 0; jj < 16; jj++) {
    float4 A = syp[(cq << 5) + 2 * jj];
    float4 B = syp[(cq << 5) + 2 * jj + 1];
    f2 yx; yx.x = A.x; yx.y = A.y;
    f2 yy; yy.x = A.z; yy.y = A.w;
    f2 yz; yz.x = B.x; yz.y = B.y;
    f2 yw; yw.x = B.z; yw.y = B.w;
    f2 cr0 = fma2(sp2(xr0.z), yz, fma2(sp2(xr0.y), yy, sp2(xr0.x) * yx));
    f2 d0 = (sp2(xr0.w) + yw) - 2.0f * cr0; d0 = max2(d0, sp2(0.0f));
    f2 cr1 = fma2(sp2(xr1.z), yz, fma2(sp2(xr1.y), yy, sp2(xr1.x) * yx));
    f2 d1 = (sp2(xr1.w) + yw) - 2.0f * cr1; d1 = max2(d1, sp2(0.0f));
    f2 cr2 = fma2(sp2(xr2.z), yz, fma2(sp2(xr2.y), yy, sp2(xr2.x) * yx));
    f2 d2_ = (sp2(xr2.w) + yw) - 2.0f * cr2; d2_ = max2(d2_, sp2(0.0f));
    f2 cr3 = fma2(sp2(xr3.z), yz, fma2(sp2(xr3.y), yy, sp2(xr3.x) * yx));
    f2 d3 = (sp2(xr3.w) + yw) - 2.0f * cr3; d3 = max2(d3, sp2(0.0f));
    racc0 = fminf(fminf(racc0, d0.x), d0.y);
    racc1 = fminf(fminf(racc1, d1.x), d1.y);
    racc2 = fminf(fminf(racc2, d2_.x), d2_.y);
    racc3 = fminf(fminf(racc3, d3.x), d3.y);
    cacc[2 * jj]     = fminf(fminf(d0.x, d1.x), fminf(d2_.x, d3.x));
    cacc[2 * jj + 1] = fminf(fminf(d0.y, d1.y), fminf(d2_.y, d3.y));
  }
  rowpart[cq * 128 + 4 * rg + 0] = racc0;
  rowpart[cq * 128 + 4 * rg + 1] = racc1;
  rowpart[cq * 128 + 4 * rg + 2] = racc2;
  rowpart[cq * 128 + 4 * rg + 3] = racc3;
#pragma unroll
  for (int m = 16; m >= 1; m >>= 1) {
    bool hi = (rg & m) != 0;
#pragma unroll
    for (int j = 0; j < m; j++) {
      float lo_v = cacc[j], hi_v = cacc[j + m];
      float mine = hi ? hi_v : lo_v;
      float send = hi ? lo_v : hi_v;
      float recv = __shfl_xor(send, m, 64);
      cacc[j] = fminf(mine, recv);
    }
  }
  float colmin = cacc[0];
  __syncthreads();
  float rv = rowpart[tid];
  rv = fminf(rv, rowpart[128 + tid]);
  rv = fminf(rv, rowpart[256 + tid]);
  rv = fminf(rv, rowpart[384 + tid]);
  red1[tid] = rv;
  red2[tid] = colmin;
  __syncthreads();
  int l = tid & 63;
  float v1 = red1[l] + red1[l + 64];
  float v2 = red2[l] + red2[l + 64];
#pragma unroll
  for (int m = 32; m >= 1; m >>= 1) {
    v1 += __shfl_xor(v1, m, 64);
    v2 += __shfl_xor(v2, m, 64);
  }
  return v1 * 0.0078125f + v2 * 0.0078125f;
}

// pop0 value for particle r, dim d of batch b (pure function)
__device__ __forceinline__ float pop0_val(int b, int r, int d) {
  if (r == 0) return 0.0f;
  U2 root = root_key();
  unsigned ridx = (unsigned)((b * 50 + r) * 3 + (d % 3));
  if (d < 3) {
    U2 k2 = split_key(root, 5, 2);
    return jax_uniform(k2, 4800, ridx, -ROTR, ROTR);
  }
  U2 k3 = split_key(root, 5, 3);
  return jax_uniform(k3, 4800, ridx, -1.0f, 1.0f);
}

// ============================================================================
// Persistent kernel (R5/R6): sentinel-word dataflow pipeline.
//   estate[it][bp][8] = {E[0..5], F, pad}; sentinel-initialized by setupperm.
//   A word is published the instant its relaxed store reaches the LLC;
//   consumers poll exactly the words they need (write-once => no ordering,
//   no flags, no fences, no publish barrier, no poll barrier).
// Residency by construction: __launch_bounds__(128,4) -> 8 blocks/CU,
// capacity 2048 >= grid 1600 -> all blocks resident, spins can't deadlock.
// ============================================================================
__global__ __launch_bounds__(128, 4) void de_loop_kernel(
    const float* __restrict__ srcb, const float* __restrict__ tgtb,
    const float* __restrict__ ynb, const unsigned* __restrict__ packg,
    float* __restrict__ estate, const float* __restrict__ source,
    float* __restrict__ out) {
  int blk = blockIdx.x;
  int b = blk / 50, p = blk % 50;
  int bp = blk;
  int tid = threadIdx.x;
  __shared__ float strial[8];
  __shared__ float pv4[4][6];
  __shared__ float4 syp[128];
  __shared__ float4 xsv[128];
  __shared__ float rowpart[512];
  __shared__ float red1[128];
  __shared__ float red2[128];
  __shared__ float fl[52];
  __shared__ float Rsh2[12];

  {
    // stage target points in pair-SoA layout (once per kernel)
    int e = tid;
    int ecq = e >> 5, rem = e & 31, jj = rem >> 1, h = rem & 1;
    int c0 = (ecq << 5) + 2 * jj, c1 = c0 + 1;
    float a0, a1, b0, b1;
    if (h == 0) {
      a0 = tgtb[(b * 128 + c0) * 3 + 0]; a1 = tgtb[(b * 128 + c1) * 3 + 0];
      b0 = tgtb[(b * 128 + c0) * 3 + 1]; b1 = tgtb[(b * 128 + c1) * 3 + 1];
    } else {
      a0 = tgtb[(b * 128 + c0) * 3 + 2]; a1 = tgtb[(b * 128 + c1) * 3 + 2];
      b0 = ynb[b * 128 + c0];            b1 = ynb[b * 128 + c1];
    }
    syp[e] = make_float4(a0, a1, b0, b1);
  }
  float s0 = srcb[(b * 128 + tid) * 3 + 0];
  float s1 = srcb[(b * 128 + tid) * 3 + 1];
  float s2 = srcb[(b * 128 + tid) * 3 + 2];

  float own_f = 0.0f;    // replicated across all threads (uniform updates)
  float own_e = 0.0f;    // valid in threads tid<6: dimension tid of E_k

  unsigned pack_next = packg[(0 * 32 + b) * 50 + p];

  for (int it = 0; it < 30; it++) {
    unsigned pack = pack_next;
    if (it < 29) pack_next = packg[((it + 1) * 32 + b) * 50 + p];  // prefetch
    int i1 = (int)(pack & 63u);
    int i2 = (int)((pack >> 6) & 63u);
    int i3 = (int)((pack >> 12) & 63u);
    unsigned mask = (pack >> 18) & 63u;

    if (it == 0) {
      if (tid < 24) {
        int u = tid / 6, d = tid % 6;
        int rows[4] = {p, i1, i2, i3};
        pv4[u][d] = pop0_val(b, rows[u], d);
      }
      __syncthreads();
      float f0 = eval_pose_core(pv4[0][0], pv4[0][1], pv4[0][2], pv4[0][3],
                                pv4[0][4], pv4[0][5],
                                s0, s1, s2, tid, syp, xsv, rowpart, red1, red2);
      if (tid < 6) {
        int d = tid;
        float mu = pv4[1][d] + 0.8f * (pv4[2][d] - pv4[3][d]);
        if (d < 3) mu = fminf(fmaxf(mu, -ROTR), ROTR);
        else       mu = fminf(fmaxf(mu, -1.0f), 1.0f);
        float pv = pv4[0][d];
        float tv = ((mask >> d) & 1u) ? mu : pv;
        strial[d] = tv;
      }
      __syncthreads();
      float tf0 = eval_pose_core(strial[0], strial[1], strial[2], strial[3],
                                 strial[4], strial[5],
                                 s0, s1, s2, tid, syp, xsv, rowpart, red1, red2);
      bool imp = tf0 < f0;
      own_f = imp ? tf0 : f0;
      if (tid < 6) own_e = imp ? strial[tid] : pv4[0][tid];
    } else {
      // ---- fused poll+read of the 3 donors' dim-d words (1 LLC round) ----
      if (tid < 6) {
        int d = tid;
        const float* eb = &estate[((size_t)(it - 1) * 1600 + b * 50) * 8];
        const unsigned* pa = (const unsigned*)&eb[i1 * 8 + d];
        const unsigned* pb = (const unsigned*)&eb[i2 * 8 + d];
        const unsigned* pc = (const unsigned*)&eb[i3 * 8 + d];
        unsigned va = uload(pa), vb = uload(pb), vc = uload(pc);
        while (va == SENTINEL || vb == SENTINEL || vc == SENTINEL) {
          __builtin_amdgcn_s_sleep(1);
          va = uload(pa); vb = uload(pb); vc = uload(pc);
        }
        float x1v = __uint_as_float(va);
        float x2v = __uint_as_float(vb);
        float x3v = __uint_as_float(vc);
        float mu = x1v + 0.8f * (x2v - x3v);
        if (d < 3) mu = fminf(fmaxf(mu, -ROTR), ROTR);
        else       mu = fminf(fmaxf(mu, -1.0f), 1.0f);
        float tv = ((mask >> d) & 1u) ? mu : own_e;
        strial[d] = tv;
      }
      __syncthreads();  // strial visible to both waves
      float tfv = eval_pose_core(strial[0], strial[1], strial[2], strial[3],
                                 strial[4], strial[5],
                                 s0, s1, s2, tid, syp, xsv, rowpart, red1, red2);
      bool imp = tfv < own_f;
      own_f = imp ? tfv : own_f;
      if (tid < 6) own_e = imp ? strial[tid] : own_e;
    }

    // ---- publish slot it: fire-and-forget word stores (no drain/barrier) ---
    float* slot = &estate[((size_t)it * 1600 + bp) * 8];
    if (tid < 6)       gstore(&slot[tid], own_e);
    else if (tid == 6) gstore(&slot[6], own_f);
  }

  // ==== final selection (redundant per block -> no extra sync hop) ====
  if (tid < 50) {
    fl[tid] = poll_word(&estate[((size_t)29 * 1600 + b * 50 + tid) * 8 + 6]);
  }
  __syncthreads();
  if (tid == 0) {
    int bi = 0;
    float best = fl[0];
    for (int q = 1; q < 50; q++)
      if (fl[q] < best) { best = fl[q]; bi = q; }
    const float* ep = &estate[((size_t)29 * 1600 + b * 50 + bi) * 8];
    float v[6];
#pragma unroll
    for (int d = 0; d < 6; d++) v[d] = poll_word(&ep[d]);  // e/f unordered
    float R[3][3];
    compute_R(v[0], v[1], v[2], R);
#pragma unroll
    for (int i = 0; i < 3; i++)
#pragma unroll
      for (int j = 0; j < 3; j++) Rsh2[i * 3 + j] = R[i][j];
    Rsh2[9] = v[3]; Rsh2[10] = v[4]; Rsh2[11] = v[5];
    if (p == 0) {
#pragma unroll
      for (int e = 0; e < 9; e++) out[b * 9 + e] = Rsh2[e];
      out[288 + b * 3 + 0] = v[3];
      out[288 + b * 3 + 1] = v[4];
      out[288 + b * 3 + 2] = v[5];
    }
  }
  __syncthreads();

  // ==== aligned transform: batch b's 16384 points across its 50 blocks ====
  for (int k = p * 128 + tid; k < 16384; k += 6400) {
    size_t gid = (size_t)b * 16384 + k;
    float a0s = source[gid * 3 + 0];
    float a1s = source[gid * 3 + 1];
    float a2s = source[gid * 3 + 2];
    float a0 = fmaf(Rsh2[2], a2s, fmaf(Rsh2[1], a1s, Rsh2[0] * a0s)) + Rsh2[9];
    float a1 = fmaf(Rsh2[5], a2s, fmaf(Rsh2[4], a1s, Rsh2[3] * a0s)) + Rsh2[10];
    float a2 = fmaf(Rsh2[8], a2s, fmaf(Rsh2[7], a1s, Rsh2[6] * a0s)) + Rsh2[11];
    out[384 + gid * 3 + 0] = a0;
    out[384 + gid * 3 + 1] = a1;
    out[384 + gid * 3 + 2] = a2;
  }
}

// ============================================================================
extern "C" void kernel_launch(void* const* d_in, const int* in_sizes, int n_in,
                              void* d_out, int out_size, void* d_ws,
                              size_t ws_size, hipStream_t stream) {
  const float* source = (const float*)d_in[0];
  const float* target = (const float*)d_in[1];
  float* out = (float*)d_out;
  char* ws = (char*)d_ws;

  // --- workspace layout ---
  // persistent (live during de_loop):
  unsigned* packg    = (unsigned*)(ws + 0);         // 192000
  float* srcb        = (float*)(ws + 192000);       // 49152
  float* tgtb        = (float*)(ws + 241152);       // 49152
  float* ynb         = (float*)(ws + 290304);       // 16384
  int* idx           = (int*)(ws + 306688);         // 1024
  unsigned* hist     = (unsigned*)(ws + 307712);    // 4096
  unsigned* basep    = (unsigned*)(ws + 414208);    // 4096
  unsigned* cursor   = (unsigned*)(ws + 418304);    // 4096
  // sort scratch (dead after setup chain) overlaid by estate (stream-ordered):
  unsigned long long* sorted = (unsigned long long*)(ws + 422400);  // 524288
  unsigned* rank_all = (unsigned*)(ws + 946688);    // 262144
  unsigned* x1buf    = (unsigned*)(ws + 1208832);   // 131072
  float* estate      = (float*)(ws + 422400);       // 1536000 (overlay)

  hipMemsetAsync(hist, 0, 4096, stream);
  hist_kernel<<<256, 256, 0, stream>>>(hist);
  prefix_kernel<<<1, 256, 0, stream>>>(hist, basep, cursor);
  scatterb_kernel<<<256, 256, 0, stream>>>(cursor, sorted);
  rank_kernel<<<256, 256, 0, stream>>>(sorted, basep, hist, rank_all, x1buf);
  idx_kernel<<<128, 256, 0, stream>>>(rank_all, x1buf, idx);
  // setupperm also sentinel-inits estate (sort scratch dead from here)
  setupperm_kernel<<<992, 128, 0, stream>>>(source, target, idx, srcb, tgtb,
                                            ynb, packg, (unsigned*)estate);

  de_loop_kernel<<<1600, 128, 0, stream>>>(srcb, tgtb, ynb, packg, estate,
                                           source, out);
}

// Round 7
// 382.670 us; speedup vs baseline: 1.0035x; 1.0035x over previous
//
#include <hip/hip_runtime.h>
#include <stdint.h>

// ============================================================================
// JAX threefry2x32 PRNG reproduction (partitionable semantics, verified R0).
// ============================================================================
struct U2 { unsigned a, b; };

__device__ __forceinline__ unsigned rotl32(unsigned v, int r) {
  return (v << r) | (v >> (32 - r));
}

__device__ __forceinline__ U2 tf(U2 k, unsigned x0, unsigned x1) {
  unsigned ks0 = k.a, ks1 = k.b, ks2 = k.a ^ k.b ^ 0x1BD11BDAu;
  x0 += ks0; x1 += ks1;
#define TFG(RA, RB, RC, RD, KA, KB, INC)                  \
  x0 += x1; x1 = rotl32(x1, RA); x1 ^= x0;                \
  x0 += x1; x1 = rotl32(x1, RB); x1 ^= x0;                \
  x0 += x1; x1 = rotl32(x1, RC); x1 ^= x0;                \
  x0 += x1; x1 = rotl32(x1, RD); x1 ^= x0;                \
  x0 += KA; x1 += KB + INC;
  TFG(13, 15, 26, 6, ks1, ks2, 1u)
  TFG(17, 29, 16, 24, ks2, ks0, 2u)
  TFG(13, 15, 26, 6, ks0, ks1, 3u)
  TFG(17, 29, 16, 24, ks1, ks2, 4u)
  TFG(13, 15, 26, 6, ks2, ks0, 5u)
#undef TFG
  U2 r; r.a = x0; r.b = x1; return r;
}

__device__ __forceinline__ U2 split_key(U2 key, int num, int j) {
  (void)num;
  return tf(key, 0u, (unsigned)j);
}
__device__ __forceinline__ unsigned random_bits(U2 key, int n, unsigned e) {
  (void)n;
  U2 r = tf(key, 0u, e);
  return r.a ^ r.b;
}

__device__ __forceinline__ U2 root_key() { U2 k; k.a = 0u; k.b = 42u; return k; }

__device__ __forceinline__ float jax_uniform(U2 key, int n, unsigned e,
                                             float minv, float maxv) {
  unsigned b = random_bits(key, n, e);
  float u = __uint_as_float((b >> 9) | 0x3f800000u) - 1.0f;
  float r = u * (maxv - minv) + minv;
  return fmaxf(minv, r);
}

#define ROTR 0.7853981633974483f
#define SENTINEL 0xFFFFFFFFu  // -NaN bit pattern; unreachable for all
                              // published values (clamped floats / positive
                              // fitness; arithmetic NaNs are 0x7FC00000)

// packed fp32 pair (lowered to v_pk_* VOP3P on gfx90a+/gfx950)
typedef float f2 __attribute__((ext_vector_type(2)));
__device__ __forceinline__ f2 sp2(float s) { f2 v; v.x = s; v.y = s; return v; }
__device__ __forceinline__ f2 fma2(f2 a, f2 b, f2 c) {
  return __builtin_elementwise_fma(a, b, c);
}
__device__ __forceinline__ f2 max2(f2 a, f2 b) {
  return __builtin_elementwise_max(a, b);
}

__device__ __forceinline__ void compute_R(float vx, float vy, float vz,
                                          float R[3][3]) {
  float nsq = vx * vx + vy * vy + vz * vz;
  float theta = sqrtf(nsq);
  if (theta < 1e-8f) {
    R[0][0] = 1.f; R[0][1] = 0.f; R[0][2] = 0.f;
    R[1][0] = 0.f; R[1][1] = 1.f; R[1][2] = 0.f;
    R[2][0] = 0.f; R[2][1] = 0.f; R[2][2] = 1.f;
    return;
  }
  float m = fmaxf(theta, 1e-8f);
  float kx = vx / m, ky = vy / m, kz = vz / m;
  float s = sinf(theta), c = cosf(theta);
  float K[3][3] = {{0.f, -kz, ky}, {kz, 0.f, -kx}, {-ky, kx, 0.f}};
  float K2[3][3];
#pragma unroll
  for (int i = 0; i < 3; i++)
#pragma unroll
    for (int j = 0; j < 3; j++)
      K2[i][j] = fmaf(K[i][2], K[2][j], fmaf(K[i][1], K[1][j], K[i][0] * K[0][j]));
  float omc = 1.0f - c;
#pragma unroll
  for (int i = 0; i < 3; i++)
#pragma unroll
    for (int j = 0; j < 3; j++)
      R[i][j] = ((i == j) ? 1.0f : 0.0f) + s * K[i][j] + omc * K2[i][j];
}

// composite sort key for stream s (0:src r1, 1:src r2, 2:tgt r1, 3:tgt r2)
__device__ __forceinline__ unsigned long long make_composite(int s, int i) {
  U2 root = root_key();
  U2 kp = split_key(root, 5, s >> 1);
  U2 key;
  if ((s & 1) == 0) {
    key = split_key(kp, 2, 1);
  } else {
    U2 kA = split_key(kp, 2, 0);
    key = split_key(kA, 2, 1);
  }
  unsigned rb = random_bits(key, 16384, (unsigned)i);
  return ((unsigned long long)rb << 32) | (unsigned)i;
}

// ============================================================================
// Agent-scope RELAXED access helpers — bypass non-coherent L1/L2, hit LLC.
// NO acquire/release fences anywhere (R3 lesson: agent fences emit
// buffer_inv/buffer_wbl2 walks; 96K of them serialized all memory traffic).
// Ordering model (R5): write-once word-granular sentinel publication —
// a word is valid iff != SENTINEL; no cross-word ordering ever needed.
// R6 lesson: NO s_sleep in hot polls — wake-up latency compounds along the
// 30-deep donor-dependency chain (268 -> 293us). Tight spin is correct here.
// ============================================================================
__device__ __forceinline__ float gload(const float* p) {
  return __hip_atomic_load(const_cast<float*>(p), __ATOMIC_RELAXED,
                           __HIP_MEMORY_SCOPE_AGENT);
}
__device__ __forceinline__ void gstore(float* p, float v) {
  __hip_atomic_store(p, v, __ATOMIC_RELAXED, __HIP_MEMORY_SCOPE_AGENT);
}
__device__ __forceinline__ unsigned uload(const unsigned* p) {
  return __hip_atomic_load(const_cast<unsigned*>(p), __ATOMIC_RELAXED,
                           __HIP_MEMORY_SCOPE_AGENT);
}

// poll a published word until it is valid (write-once, sentinel-initialized)
__device__ __forceinline__ float poll_word(const float* p) {
  const unsigned* up = (const unsigned*)p;
  unsigned v = uload(up);
  while (v == SENTINEL) v = uload(up);
  return __uint_as_float(v);
}

// ============================================================================
// Bucket-sort rank pipeline (verified R3-R6/R10) — WIDE dispatches.
// ============================================================================
__global__ __launch_bounds__(256) void hist_kernel(unsigned* __restrict__ hist) {
  int gid = blockIdx.x * 256 + threadIdx.x;  // 65536
  int s = gid >> 14, i = gid & 16383;
  unsigned long long c = make_composite(s, i);
  unsigned bucket = (unsigned)(c >> 56);
  atomicAdd(&hist[s * 256 + bucket], 1u);
}

__global__ __launch_bounds__(256) void prefix_kernel(
    const unsigned* __restrict__ hist, unsigned* __restrict__ base,
    unsigned* __restrict__ cursor) {
  __shared__ unsigned h[4][256];
  int t = threadIdx.x;
#pragma unroll
  for (int s = 0; s < 4; s++) h[s][t] = hist[s * 256 + t];
  __syncthreads();
#pragma unroll
  for (int s = 0; s < 4; s++) {
    unsigned acc = 0;
    for (int j = 0; j < 256; j++) acc += (j < t) ? h[s][j] : 0u;
    base[s * 256 + t] = acc;
    cursor[s * 256 + t] = acc;
  }
}

__global__ __launch_bounds__(256) void scatterb_kernel(
    unsigned* __restrict__ cursor, unsigned long long* __restrict__ sorted) {
  int gid = blockIdx.x * 256 + threadIdx.x;  // 65536
  int s = gid >> 14, i = gid & 16383;
  unsigned long long c = make_composite(s, i);
  unsigned bucket = (unsigned)(c >> 56);
  unsigned pos = atomicAdd(&cursor[s * 256 + bucket], 1u);
  sorted[(s << 14) + pos] = c;
}

__global__ __launch_bounds__(256) void rank_kernel(
    const unsigned long long* __restrict__ sorted,
    const unsigned* __restrict__ base, const unsigned* __restrict__ hist,
    unsigned* __restrict__ rank_all, unsigned* __restrict__ x1buf) {
  int gid = blockIdx.x * 256 + threadIdx.x;  // 65536
  int s = gid >> 14, k = gid & 16383;
  unsigned long long c = sorted[(s << 14) + k];
  unsigned bucket = (unsigned)(c >> 56);
  unsigned b0 = base[s * 256 + bucket];
  unsigned cnt = hist[s * 256 + bucket];
  unsigned less = 0;
  for (unsigned j = 0; j < cnt; j++)
    less += (sorted[(s << 14) + b0 + j] < c) ? 1u : 0u;
  unsigned i = (unsigned)(c & 0xffffffffull);
  unsigned rank = b0 + less;
  if ((s & 1) == 0) x1buf[((s >> 1) << 14) + rank] = i;
  else              rank_all[(s << 14) + i] = rank;
}

__global__ __launch_bounds__(256) void idx_kernel(
    const unsigned* __restrict__ rank_all, const unsigned* __restrict__ x1buf,
    int* __restrict__ idx) {
  int gid = blockIdx.x * 256 + threadIdx.x;  // 32768
  int perm = gid >> 14, i = gid & 16383;
  unsigned r = rank_all[((perm * 2 + 1) << 14) + i];
  if (r < 128u) idx[perm * 128 + (int)r] = (int)x1buf[(perm << 14) + i];
}

// ============================================================================
// setup (blocks 0..31) + DE-schedule precompute (blocks 32..991).
// Also sentinel-initializes estate (folds away the hipMemsetAsync dispatch;
// kernel-end L2 writeback makes these normal stores visible to de_loop's
// LLC-direct atomic polls).
// ============================================================================
__global__ __launch_bounds__(128) void setupperm_kernel(
    const float* __restrict__ source, const float* __restrict__ target,
    const int* __restrict__ idx, float* __restrict__ src,
    float* __restrict__ tgt, float* __restrict__ yn,
    unsigned* __restrict__ packg, unsigned* __restrict__ ewords) {
  int blk = blockIdx.x;
  int tid = threadIdx.x;
  // sentinel-init estate: 384000 words over 992*128 = 126976 threads
  for (int i = blk * 128 + tid; i < 384000; i += 126976)
    ewords[i] = SENTINEL;
  if (blk < 32) {
    int b = blk;
    int is = idx[tid], it = idx[128 + tid];
#pragma unroll
    for (int d = 0; d < 3; d++)
      src[(b * 128 + tid) * 3 + d] = source[((size_t)b * 16384 + is) * 3 + d];
    float y0 = target[((size_t)b * 16384 + it) * 3 + 0];
    float y1 = target[((size_t)b * 16384 + it) * 3 + 1];
    float y2 = target[((size_t)b * 16384 + it) * 3 + 2];
    tgt[(b * 128 + tid) * 3 + 0] = y0;
    tgt[(b * 128 + tid) * 3 + 1] = y1;
    tgt[(b * 128 + tid) * 3 + 2] = y2;
    yn[b * 128 + tid] = y0 * y0 + y1 * y1 + y2 * y2;
    return;
  }
  int blk2 = blk - 32;  // 960
  int it = blk2 >> 5, b = blk2 & 31;
  __shared__ unsigned pbits[3][64];
  __shared__ int lperm[3][64];
  U2 root = root_key();
  U2 kloop = split_key(root, 5, 4);
  U2 kit = split_key(kloop, 30, it);
  U2 ka = split_key(kit, 3, 0);
  for (int e = tid; e < 150; e += 128) {
    int r = e / 50, q = e % 50;
    U2 pk = split_key(ka, 96, r * 32 + b);
    U2 sub = split_key(pk, 2, 1);
    pbits[r][q] = random_bits(sub, 50, (unsigned)q);
  }
  __syncthreads();
  for (int e = tid; e < 150; e += 128) {
    int r = e / 50, q = e % 50;
    unsigned bq = pbits[r][q];
    int cnt = 0;
    for (int j = 0; j < 50; j++) {
      unsigned bj = pbits[r][j];
      cnt += (bj < bq || (bj == bq && j < q)) ? 1 : 0;
    }
    lperm[r][cnt] = q;
  }
  __syncthreads();
  if (tid < 50) {
    int p = tid, bp = b * 50 + p;
    U2 kb = split_key(kit, 3, 1);
    U2 kc = split_key(kit, 3, 2);
    U2 kc1 = split_key(kc, 2, 0), kc2 = split_key(kc, 2, 1);
    unsigned hb = random_bits(kc1, 1600, (unsigned)bp);
    unsigned lb = random_bits(kc2, 1600, (unsigned)bp);
    int jr = (int)((((hb % 6u) * 4u) + (lb % 6u)) % 6u);
    unsigned mask = 0;
#pragma unroll
    for (int d = 0; d < 6; d++) {
      unsigned rb = random_bits(kb, 9600, (unsigned)(bp * 6 + d));
      float u = __uint_as_float((rb >> 9) | 0x3f800000u) - 1.0f;
      if ((u < 0.9f) || (d == jr)) mask |= (1u << d);
    }
    unsigned pack = (unsigned)lperm[0][p] | ((unsigned)lperm[1][p] << 6) |
                    ((unsigned)lperm[2][p] << 12) | (mask << 18);
    packg[(it * 32 + b) * 50 + p] = pack;
  }
}

// ============================================================================
// Chamfer eval core — packed-fp32 (R6/R7). Per 2-column pair: dot/d2
// arithmetic in f2 (v_pk_fma/add/mul); min/max chain scalar. Numerics are
// element-identical to the verified scalar path (same fma/add/mul sequences
// per column; racc min visits columns in ascending order).
// LDS layout syp: per cq-group of 32 cols, 16 pairs x 2 float4:
//   syp[(cq<<5)+2*jj+0] = {yx0, yx1, yy0, yy1}
//   syp[(cq<<5)+2*jj+1] = {yz0, yz1, yw0, yw1}
// ============================================================================
__device__ __forceinline__ float eval_pose_core(
    float p0, float p1, float p2, float p3, float p4, float p5,
    float s0, float s1, float s2, int tid, const float4* syp, float4* xsv,
    float* rowpart, float* red1, float* red2) {
  float Rm[3][3];
  compute_R(p0, p1, p2, Rm);
  float x0 = fmaf(Rm[0][2], s2, fmaf(Rm[0][1], s1, Rm[0][0] * s0)) + p3;
  float x1 = fmaf(Rm[1][2], s2, fmaf(Rm[1][1], s1, Rm[1][0] * s0)) + p4;
  float x2 = fmaf(Rm[2][2], s2, fmaf(Rm[2][1], s1, Rm[2][0] * s0)) + p5;
  float xn = x0 * x0 + x1 * x1 + x2 * x2;
  xsv[tid] = make_float4(x0, x1, x2, xn);
  __syncthreads();
  int rg = tid & 31, cq = tid >> 5;
  float4 xr0 = xsv[4 * rg + 0];
  float4 xr1 = xsv[4 * rg + 1];
  float4 xr2 = xsv[4 * rg + 2];
  float4 xr3 = xsv[4 * rg + 3];
  float racc0 = 3.402823466e38f, racc1 = 3.402823466e38f;
  float racc2 = 3.402823466e38f, racc3 = 3.402823466e38f;
  float cacc[32];
#pragma unroll
  for (int jj = 0; jj < 16; jj++) {
    float4 A = syp[(cq << 5) + 2 * jj];
    float4 B = syp[(cq << 5) + 2 * jj + 1];
    f2 yx; yx.x = A.x; yx.y = A.y;
    f2 yy; yy.x = A.z; yy.y = A.w;
    f2 yz; yz.x = B.x; yz.y = B.y;
    f2 yw; yw.x = B.z; yw.y = B.w;
    f2 cr0 = fma2(sp2(xr0.z), yz, fma2(sp2(xr0.y), yy, sp2(xr0.x) * yx));
    f2 d0 = (sp2(xr0.w) + yw) - 2.0f * cr0; d0 = max2(d0, sp2(0.0f));
    f2 cr1 = fma2(sp2(xr1.z), yz, fma2(sp2(xr1.y), yy, sp2(xr1.x) * yx));
    f2 d1 = (sp2(xr1.w) + yw) - 2.0f * cr1; d1 = max2(d1, sp2(0.0f));
    f2 cr2 = fma2(sp2(xr2.z), yz, fma2(sp2(xr2.y), yy, sp2(xr2.x) * yx));
    f2 d2_ = (sp2(xr2.w) + yw) - 2.0f * cr2; d2_ = max2(d2_, sp2(0.0f));
    f2 cr3 = fma2(sp2(xr3.z), yz, fma2(sp2(xr3.y), yy, sp2(xr3.x) * yx));
    f2 d3 = (sp2(xr3.w) + yw) - 2.0f * cr3; d3 = max2(d3, sp2(0.0f));
    racc0 = fminf(fminf(racc0, d0.x), d0.y);
    racc1 = fminf(fminf(racc1, d1.x), d1.y);
    racc2 = fminf(fminf(racc2, d2_.x), d2_.y);
    racc3 = fminf(fminf(racc3, d3.x), d3.y);
    cacc[2 * jj]     = fminf(fminf(d0.x, d1.x), fminf(d2_.x, d3.x));
    cacc[2 * jj + 1] = fminf(fminf(d0.y, d1.y), fminf(d2_.y, d3.y));
  }
  rowpart[cq * 128 + 4 * rg + 0] = racc0;
  rowpart[cq * 128 + 4 * rg + 1] = racc1;
  rowpart[cq * 128 + 4 * rg + 2] = racc2;
  rowpart[cq * 128 + 4 * rg + 3] = racc3;
#pragma unroll
  for (int m = 16; m >= 1; m >>= 1) {
    bool hi = (rg & m) != 0;
#pragma unroll
    for (int j = 0; j < m; j++) {
      float lo_v = cacc[j], hi_v = cacc[j + m];
      float mine = hi ? hi_v : lo_v;
      float send = hi ? lo_v : hi_v;
      float recv = __shfl_xor(send, m, 64);
      cacc[j] = fminf(mine, recv);
    }
  }
  float colmin = cacc[0];
  __syncthreads();
  float rv = rowpart[tid];
  rv = fminf(rv, rowpart[128 + tid]);
  rv = fminf(rv, rowpart[256 + tid]);
  rv = fminf(rv, rowpart[384 + tid]);
  red1[tid] = rv;
  red2[tid] = colmin;
  __syncthreads();
  int l = tid & 63;
  float v1 = red1[l] + red1[l + 64];
  float v2 = red2[l] + red2[l + 64];
#pragma unroll
  for (int m = 32; m >= 1; m >>= 1) {
    v1 += __shfl_xor(v1, m, 64);
    v2 += __shfl_xor(v2, m, 64);
  }
  return v1 * 0.0078125f + v2 * 0.0078125f;
}

// pop0 value for particle r, dim d of batch b (pure function)
__device__ __forceinline__ float pop0_val(int b, int r, int d) {
  if (r == 0) return 0.0f;
  U2 root = root_key();
  unsigned ridx = (unsigned)((b * 50 + r) * 3 + (d % 3));
  if (d < 3) {
    U2 k2 = split_key(root, 5, 2);
    return jax_uniform(k2, 4800, ridx, -ROTR, ROTR);
  }
  U2 k3 = split_key(root, 5, 3);
  return jax_uniform(k3, 4800, ridx, -1.0f, 1.0f);
}

// ============================================================================
// Persistent kernel (R5/R7): sentinel-word dataflow pipeline, tight spins.
//   estate[it][bp][8] = {E[0..5], F, pad}; sentinel-initialized by setupperm.
//   Write-once words => no ordering, no flags, no fences, no barriers.
// Residency by construction: __launch_bounds__(128,4) -> 8 blocks/CU,
// capacity 2048 >= grid 1600 -> all blocks resident, spins can't deadlock.
// ============================================================================
__global__ __launch_bounds__(128, 4) void de_loop_kernel(
    const float* __restrict__ srcb, const float* __restrict__ tgtb,
    const float* __restrict__ ynb, const unsigned* __restrict__ packg,
    float* __restrict__ estate, const float* __restrict__ source,
    float* __restrict__ out) {
  int blk = blockIdx.x;
  int b = blk / 50, p = blk % 50;
  int bp = blk;
  int tid = threadIdx.x;
  __shared__ float strial[8];
  __shared__ float pv4[4][6];
  __shared__ float4 syp[128];
  __shared__ float4 xsv[128];
  __shared__ float rowpart[512];
  __shared__ float red1[128];
  __shared__ float red2[128];
  __shared__ float fl[52];
  __shared__ float Rsh2[12];

  {
    // stage target points in pair-SoA layout (once per kernel)
    int e = tid;
    int ecq = e >> 5, rem = e & 31, jj = rem >> 1, h = rem & 1;
    int c0 = (ecq << 5) + 2 * jj, c1 = c0 + 1;
    float a0, a1, b0, b1;
    if (h == 0) {
      a0 = tgtb[(b * 128 + c0) * 3 + 0]; a1 = tgtb[(b * 128 + c1) * 3 + 0];
      b0 = tgtb[(b * 128 + c0) * 3 + 1]; b1 = tgtb[(b * 128 + c1) * 3 + 1];
    } else {
      a0 = tgtb[(b * 128 + c0) * 3 + 2]; a1 = tgtb[(b * 128 + c1) * 3 + 2];
      b0 = ynb[b * 128 + c0];            b1 = ynb[b * 128 + c1];
    }
    syp[e] = make_float4(a0, a1, b0, b1);
  }
  float s0 = srcb[(b * 128 + tid) * 3 + 0];
  float s1 = srcb[(b * 128 + tid) * 3 + 1];
  float s2 = srcb[(b * 128 + tid) * 3 + 2];

  float own_f = 0.0f;    // replicated across all threads (uniform updates)
  float own_e = 0.0f;    // valid in threads tid<6: dimension tid of E_k

  unsigned pack_next = packg[(0 * 32 + b) * 50 + p];

  for (int it = 0; it < 30; it++) {
    unsigned pack = pack_next;
    if (it < 29) pack_next = packg[((it + 1) * 32 + b) * 50 + p];  // prefetch
    int i1 = (int)(pack & 63u);
    int i2 = (int)((pack >> 6) & 63u);
    int i3 = (int)((pack >> 12) & 63u);
    unsigned mask = (pack >> 18) & 63u;

    if (it == 0) {
      if (tid < 24) {
        int u = tid / 6, d = tid % 6;
        int rows[4] = {p, i1, i2, i3};
        pv4[u][d] = pop0_val(b, rows[u], d);
      }
      __syncthreads();
      float f0 = eval_pose_core(pv4[0][0], pv4[0][1], pv4[0][2], pv4[0][3],
                                pv4[0][4], pv4[0][5],
                                s0, s1, s2, tid, syp, xsv, rowpart, red1, red2);
      if (tid < 6) {
        int d = tid;
        float mu = pv4[1][d] + 0.8f * (pv4[2][d] - pv4[3][d]);
        if (d < 3) mu = fminf(fmaxf(mu, -ROTR), ROTR);
        else       mu = fminf(fmaxf(mu, -1.0f), 1.0f);
        float pv = pv4[0][d];
        float tv = ((mask >> d) & 1u) ? mu : pv;
        strial[d] = tv;
      }
      __syncthreads();
      float tf0 = eval_pose_core(strial[0], strial[1], strial[2], strial[3],
                                 strial[4], strial[5],
                                 s0, s1, s2, tid, syp, xsv, rowpart, red1, red2);
      bool imp = tf0 < f0;
      own_f = imp ? tf0 : f0;
      if (tid < 6) own_e = imp ? strial[tid] : pv4[0][tid];
    } else {
      // ---- fused poll+read of the 3 donors' dim-d words (tight spin) ----
      if (tid < 6) {
        int d = tid;
        const float* eb = &estate[((size_t)(it - 1) * 1600 + b * 50) * 8];
        const unsigned* pa = (const unsigned*)&eb[i1 * 8 + d];
        const unsigned* pb = (const unsigned*)&eb[i2 * 8 + d];
        const unsigned* pc = (const unsigned*)&eb[i3 * 8 + d];
        unsigned va = uload(pa), vb = uload(pb), vc = uload(pc);
        while (va == SENTINEL || vb == SENTINEL || vc == SENTINEL) {
          va = uload(pa); vb = uload(pb); vc = uload(pc);
        }
        float x1v = __uint_as_float(va);
        float x2v = __uint_as_float(vb);
        float x3v = __uint_as_float(vc);
        float mu = x1v + 0.8f * (x2v - x3v);
        if (d < 3) mu = fminf(fmaxf(mu, -ROTR), ROTR);
        else       mu = fminf(fmaxf(mu, -1.0f), 1.0f);
        float tv = ((mask >> d) & 1u) ? mu : own_e;
        strial[d] = tv;
      }
      __syncthreads();  // strial visible to both waves
      float tfv = eval_pose_core(strial[0], strial[1], strial[2], strial[3],
                                 strial[4], strial[5],
                                 s0, s1, s2, tid, syp, xsv, rowpart, red1, red2);
      bool imp = tfv < own_f;
      own_f = imp ? tfv : own_f;
      if (tid < 6) own_e = imp ? strial[tid] : own_e;
    }

    // ---- publish slot it: fire-and-forget word stores (no drain/barrier) ---
    float* slot = &estate[((size_t)it * 1600 + bp) * 8];
    if (tid < 6)       gstore(&slot[tid], own_e);
    else if (tid == 6) gstore(&slot[6], own_f);
  }

  // ==== final selection (redundant per block -> no extra sync hop) ====
  if (tid < 50) {
    fl[tid] = poll_word(&estate[((size_t)29 * 1600 + b * 50 + tid) * 8 + 6]);
  }
  __syncthreads();
  if (tid == 0) {
    int bi = 0;
    float best = fl[0];
    for (int q = 1; q < 50; q++)
      if (fl[q] < best) { best = fl[q]; bi = q; }
    const float* ep = &estate[((size_t)29 * 1600 + b * 50 + bi) * 8];
    float v[6];
#pragma unroll
    for (int d = 0; d < 6; d++) v[d] = poll_word(&ep[d]);  // e/f unordered
    float R[3][3];
    compute_R(v[0], v[1], v[2], R);
#pragma unroll
    for (int i = 0; i < 3; i++)
#pragma unroll
      for (int j = 0; j < 3; j++) Rsh2[i * 3 + j] = R[i][j];
    Rsh2[9] = v[3]; Rsh2[10] = v[4]; Rsh2[11] = v[5];
    if (p == 0) {
#pragma unroll
      for (int e = 0; e < 9; e++) out[b * 9 + e] = Rsh2[e];
      out[288 + b * 3 + 0] = v[3];
      out[288 + b * 3 + 1] = v[4];
      out[288 + b * 3 + 2] = v[5];
    }
  }
  __syncthreads();

  // ==== aligned transform: batch b's 16384 points across its 50 blocks ====
  for (int k = p * 128 + tid; k < 16384; k += 6400) {
    size_t gid = (size_t)b * 16384 + k;
    float a0s = source[gid * 3 + 0];
    float a1s = source[gid * 3 + 1];
    float a2s = source[gid * 3 + 2];
    float a0 = fmaf(Rsh2[2], a2s, fmaf(Rsh2[1], a1s, Rsh2[0] * a0s)) + Rsh2[9];
    float a1 = fmaf(Rsh2[5], a2s, fmaf(Rsh2[4], a1s, Rsh2[3] * a0s)) + Rsh2[10];
    float a2 = fmaf(Rsh2[8], a2s, fmaf(Rsh2[7], a1s, Rsh2[6] * a0s)) + Rsh2[11];
    out[384 + gid * 3 + 0] = a0;
    out[384 + gid * 3 + 1] = a1;
    out[384 + gid * 3 + 2] = a2;
  }
}

// ============================================================================
extern "C" void kernel_launch(void* const* d_in, const int* in_sizes, int n_in,
                              void* d_out, int out_size, void* d_ws,
                              size_t ws_size, hipStream_t stream) {
  const float* source = (const float*)d_in[0];
  const float* target = (const float*)d_in[1];
  float* out = (float*)d_out;
  char* ws = (char*)d_ws;

  // --- workspace layout ---
  // persistent (live during de_loop):
  unsigned* packg    = (unsigned*)(ws + 0);         // 192000
  float* srcb        = (float*)(ws + 192000);       // 49152
  float* tgtb        = (float*)(ws + 241152);       // 49152
  float* ynb         = (float*)(ws + 290304);       // 16384
  int* idx           = (int*)(ws + 306688);         // 1024
  unsigned* hist     = (unsigned*)(ws + 307712);    // 4096
  unsigned* basep    = (unsigned*)(ws + 414208);    // 4096
  unsigned* cursor   = (unsigned*)(ws + 418304);    // 4096
  // sort scratch (dead after setup chain) overlaid by estate (stream-ordered):
  unsigned long long* sorted = (unsigned long long*)(ws + 422400);  // 524288
  unsigned* rank_all = (unsigned*)(ws + 946688);    // 262144
  unsigned* x1buf    = (unsigned*)(ws + 1208832);   // 131072
  float* estate      = (float*)(ws + 422400);       // 1536000 (overlay)

  hipMemsetAsync(hist, 0, 4096, stream);
  hist_kernel<<<256, 256, 0, stream>>>(hist);
  prefix_kernel<<<1, 256, 0, stream>>>(hist, basep, cursor);
  scatterb_kernel<<<256, 256, 0, stream>>>(cursor, sorted);
  rank_kernel<<<256, 256, 0, stream>>>(sorted, basep, hist, rank_all, x1buf);
  idx_kernel<<<128, 256, 0, stream>>>(rank_all, x1buf, idx);
  // setupperm also sentinel-inits estate (sort scratch dead from here)
  setupperm_kernel<<<992, 128, 0, stream>>>(source, target, idx, srcb, tgtb,
                                            ynb, packg, (unsigned*)estate);

  de_loop_kernel<<<1600, 128, 0, stream>>>(srcb, tgtb, ynb, packg, estate,
                                           source, out);
}

// Round 8
// 361.726 us; speedup vs baseline: 1.0616x; 1.0579x over previous
//
#include <hip/hip_runtime.h>
#include <stdint.h>

// ============================================================================
// JAX threefry2x32 PRNG reproduction (partitionable semantics, verified R0).
// ============================================================================
struct U2 { unsigned a, b; };

__device__ __forceinline__ unsigned rotl32(unsigned v, int r) {
  return (v << r) | (v >> (32 - r));
}

__device__ __forceinline__ U2 tf(U2 k, unsigned x0, unsigned x1) {
  unsigned ks0 = k.a, ks1 = k.b, ks2 = k.a ^ k.b ^ 0x1BD11BDAu;
  x0 += ks0; x1 += ks1;
#define TFG(RA, RB, RC, RD, KA, KB, INC)                  \
  x0 += x1; x1 = rotl32(x1, RA); x1 ^= x0;                \
  x0 += x1; x1 = rotl32(x1, RB); x1 ^= x0;                \
  x0 += x1; x1 = rotl32(x1, RC); x1 ^= x0;                \
  x0 += x1; x1 = rotl32(x1, RD); x1 ^= x0;                \
  x0 += KA; x1 += KB + INC;
  TFG(13, 15, 26, 6, ks1, ks2, 1u)
  TFG(17, 29, 16, 24, ks2, ks0, 2u)
  TFG(13, 15, 26, 6, ks0, ks1, 3u)
  TFG(17, 29, 16, 24, ks1, ks2, 4u)
  TFG(13, 15, 26, 6, ks2, ks0, 5u)
#undef TFG
  U2 r; r.a = x0; r.b = x1; return r;
}

__device__ __forceinline__ U2 split_key(U2 key, int num, int j) {
  (void)num;
  return tf(key, 0u, (unsigned)j);
}
__device__ __forceinline__ unsigned random_bits(U2 key, int n, unsigned e) {
  (void)n;
  U2 r = tf(key, 0u, e);
  return r.a ^ r.b;
}

__device__ __forceinline__ U2 root_key() { U2 k; k.a = 0u; k.b = 42u; return k; }

__device__ __forceinline__ float jax_uniform(U2 key, int n, unsigned e,
                                             float minv, float maxv) {
  unsigned b = random_bits(key, n, e);
  float u = __uint_as_float((b >> 9) | 0x3f800000u) - 1.0f;
  float r = u * (maxv - minv) + minv;
  return fmaxf(minv, r);
}

#define ROTR 0.7853981633974483f
#define SENTINEL 0xFFFFFFFFu  // -NaN bit pattern; unreachable for all
                              // published values (clamped floats / positive
                              // fitness; arithmetic NaNs are 0x7FC00000)

__device__ __forceinline__ void compute_R(float vx, float vy, float vz,
                                          float R[3][3]) {
  float nsq = vx * vx + vy * vy + vz * vz;
  float theta = sqrtf(nsq);
  if (theta < 1e-8f) {
    R[0][0] = 1.f; R[0][1] = 0.f; R[0][2] = 0.f;
    R[1][0] = 0.f; R[1][1] = 1.f; R[1][2] = 0.f;
    R[2][0] = 0.f; R[2][1] = 0.f; R[2][2] = 1.f;
    return;
  }
  float m = fmaxf(theta, 1e-8f);
  float kx = vx / m, ky = vy / m, kz = vz / m;
  float s = sinf(theta), c = cosf(theta);
  float K[3][3] = {{0.f, -kz, ky}, {kz, 0.f, -kx}, {-ky, kx, 0.f}};
  float K2[3][3];
#pragma unroll
  for (int i = 0; i < 3; i++)
#pragma unroll
    for (int j = 0; j < 3; j++)
      K2[i][j] = fmaf(K[i][2], K[2][j], fmaf(K[i][1], K[1][j], K[i][0] * K[0][j]));
  float omc = 1.0f - c;
#pragma unroll
  for (int i = 0; i < 3; i++)
#pragma unroll
    for (int j = 0; j < 3; j++)
      R[i][j] = ((i == j) ? 1.0f : 0.0f) + s * K[i][j] + omc * K2[i][j];
}

// composite sort key for stream s (0:src r1, 1:src r2, 2:tgt r1, 3:tgt r2)
__device__ __forceinline__ unsigned long long make_composite(int s, int i) {
  U2 root = root_key();
  U2 kp = split_key(root, 5, s >> 1);
  U2 key;
  if ((s & 1) == 0) {
    key = split_key(kp, 2, 1);
  } else {
    U2 kA = split_key(kp, 2, 0);
    key = split_key(kA, 2, 1);
  }
  unsigned rb = random_bits(key, 16384, (unsigned)i);
  return ((unsigned long long)rb << 32) | (unsigned)i;
}

// ============================================================================
// Agent-scope RELAXED access helpers — bypass non-coherent L1/L2, hit LLC.
// NO acquire/release fences anywhere (R3 lesson: agent fences emit
// buffer_inv/buffer_wbl2 walks; 96K of them serialized all memory traffic).
// Ordering model (R5): write-once word-granular sentinel publication —
// a word is valid iff != SENTINEL; no cross-word ordering ever needed.
// R6/R7 lessons: s_sleep in hot polls is neutral-to-harmful; packed-fp32
// eval cuts VALU issue 26% but RAISES wall (cascade is latency-bound, not
// issue-bound) — scalar eval restored.
// ============================================================================
__device__ __forceinline__ float gload(const float* p) {
  return __hip_atomic_load(const_cast<float*>(p), __ATOMIC_RELAXED,
                           __HIP_MEMORY_SCOPE_AGENT);
}
__device__ __forceinline__ void gstore(float* p, float v) {
  __hip_atomic_store(p, v, __ATOMIC_RELAXED, __HIP_MEMORY_SCOPE_AGENT);
}
__device__ __forceinline__ unsigned uload(const unsigned* p) {
  return __hip_atomic_load(const_cast<unsigned*>(p), __ATOMIC_RELAXED,
                           __HIP_MEMORY_SCOPE_AGENT);
}

// poll a published word until it is valid (write-once, sentinel-initialized)
__device__ __forceinline__ float poll_word(const float* p) {
  const unsigned* up = (const unsigned*)p;
  unsigned v = uload(up);
  while (v == SENTINEL) v = uload(up);
  return __uint_as_float(v);
}

// ============================================================================
// Bucket-sort rank pipeline (verified R3-R6/R10) — WIDE dispatches.
// ============================================================================
__global__ __launch_bounds__(256) void hist_kernel(unsigned* __restrict__ hist) {
  int gid = blockIdx.x * 256 + threadIdx.x;  // 65536
  int s = gid >> 14, i = gid & 16383;
  unsigned long long c = make_composite(s, i);
  unsigned bucket = (unsigned)(c >> 56);
  atomicAdd(&hist[s * 256 + bucket], 1u);
}

__global__ __launch_bounds__(256) void prefix_kernel(
    const unsigned* __restrict__ hist, unsigned* __restrict__ base,
    unsigned* __restrict__ cursor) {
  __shared__ unsigned h[4][256];
  int t = threadIdx.x;
#pragma unroll
  for (int s = 0; s < 4; s++) h[s][t] = hist[s * 256 + t];
  __syncthreads();
#pragma unroll
  for (int s = 0; s < 4; s++) {
    unsigned acc = 0;
    for (int j = 0; j < 256; j++) acc += (j < t) ? h[s][j] : 0u;
    base[s * 256 + t] = acc;
    cursor[s * 256 + t] = acc;
  }
}

__global__ __launch_bounds__(256) void scatterb_kernel(
    unsigned* __restrict__ cursor, unsigned long long* __restrict__ sorted) {
  int gid = blockIdx.x * 256 + threadIdx.x;  // 65536
  int s = gid >> 14, i = gid & 16383;
  unsigned long long c = make_composite(s, i);
  unsigned bucket = (unsigned)(c >> 56);
  unsigned pos = atomicAdd(&cursor[s * 256 + bucket], 1u);
  sorted[(s << 14) + pos] = c;
}

__global__ __launch_bounds__(256) void rank_kernel(
    const unsigned long long* __restrict__ sorted,
    const unsigned* __restrict__ base, const unsigned* __restrict__ hist,
    unsigned* __restrict__ rank_all, unsigned* __restrict__ x1buf) {
  int gid = blockIdx.x * 256 + threadIdx.x;  // 65536
  int s = gid >> 14, k = gid & 16383;
  unsigned long long c = sorted[(s << 14) + k];
  unsigned bucket = (unsigned)(c >> 56);
  unsigned b0 = base[s * 256 + bucket];
  unsigned cnt = hist[s * 256 + bucket];
  unsigned less = 0;
  for (unsigned j = 0; j < cnt; j++)
    less += (sorted[(s << 14) + b0 + j] < c) ? 1u : 0u;
  unsigned i = (unsigned)(c & 0xffffffffull);
  unsigned rank = b0 + less;
  if ((s & 1) == 0) x1buf[((s >> 1) << 14) + rank] = i;
  else              rank_all[(s << 14) + i] = rank;
}

__global__ __launch_bounds__(256) void idx_kernel(
    const unsigned* __restrict__ rank_all, const unsigned* __restrict__ x1buf,
    int* __restrict__ idx) {
  int gid = blockIdx.x * 256 + threadIdx.x;  // 32768
  int perm = gid >> 14, i = gid & 16383;
  unsigned r = rank_all[((perm * 2 + 1) << 14) + i];
  if (r < 128u) idx[perm * 128 + (int)r] = (int)x1buf[(perm << 14) + i];
}

// ============================================================================
// setup (blocks 0..31) + DE-schedule precompute (blocks 32..991).
// Also sentinel-initializes estate (folds away the hipMemsetAsync dispatch;
// kernel-end L2 writeback makes these normal stores visible to de_loop's
// LLC-direct atomic polls).
// ============================================================================
__global__ __launch_bounds__(128) void setupperm_kernel(
    const float* __restrict__ source, const float* __restrict__ target,
    const int* __restrict__ idx, float* __restrict__ src,
    float* __restrict__ tgt, float* __restrict__ yn,
    unsigned* __restrict__ packg, unsigned* __restrict__ ewords) {
  int blk = blockIdx.x;
  int tid = threadIdx.x;
  // sentinel-init estate: 384000 words over 992*128 = 126976 threads
  for (int i = blk * 128 + tid; i < 384000; i += 126976)
    ewords[i] = SENTINEL;
  if (blk < 32) {
    int b = blk;
    int is = idx[tid], it = idx[128 + tid];
#pragma unroll
    for (int d = 0; d < 3; d++)
      src[(b * 128 + tid) * 3 + d] = source[((size_t)b * 16384 + is) * 3 + d];
    float y0 = target[((size_t)b * 16384 + it) * 3 + 0];
    float y1 = target[((size_t)b * 16384 + it) * 3 + 1];
    float y2 = target[((size_t)b * 16384 + it) * 3 + 2];
    tgt[(b * 128 + tid) * 3 + 0] = y0;
    tgt[(b * 128 + tid) * 3 + 1] = y1;
    tgt[(b * 128 + tid) * 3 + 2] = y2;
    yn[b * 128 + tid] = y0 * y0 + y1 * y1 + y2 * y2;
    return;
  }
  int blk2 = blk - 32;  // 960
  int it = blk2 >> 5, b = blk2 & 31;
  __shared__ unsigned pbits[3][64];
  __shared__ int lperm[3][64];
  U2 root = root_key();
  U2 kloop = split_key(root, 5, 4);
  U2 kit = split_key(kloop, 30, it);
  U2 ka = split_key(kit, 3, 0);
  for (int e = tid; e < 150; e += 128) {
    int r = e / 50, q = e % 50;
    U2 pk = split_key(ka, 96, r * 32 + b);
    U2 sub = split_key(pk, 2, 1);
    pbits[r][q] = random_bits(sub, 50, (unsigned)q);
  }
  __syncthreads();
  for (int e = tid; e < 150; e += 128) {
    int r = e / 50, q = e % 50;
    unsigned bq = pbits[r][q];
    int cnt = 0;
    for (int j = 0; j < 50; j++) {
      unsigned bj = pbits[r][j];
      cnt += (bj < bq || (bj == bq && j < q)) ? 1 : 0;
    }
    lperm[r][cnt] = q;
  }
  __syncthreads();
  if (tid < 50) {
    int p = tid, bp = b * 50 + p;
    U2 kb = split_key(kit, 3, 1);
    U2 kc = split_key(kit, 3, 2);
    U2 kc1 = split_key(kc, 2, 0), kc2 = split_key(kc, 2, 1);
    unsigned hb = random_bits(kc1, 1600, (unsigned)bp);
    unsigned lb = random_bits(kc2, 1600, (unsigned)bp);
    int jr = (int)((((hb % 6u) * 4u) + (lb % 6u)) % 6u);
    unsigned mask = 0;
#pragma unroll
    for (int d = 0; d < 6; d++) {
      unsigned rb = random_bits(kb, 9600, (unsigned)(bp * 6 + d));
      float u = __uint_as_float((rb >> 9) | 0x3f800000u) - 1.0f;
      if ((u < 0.9f) || (d == jr)) mask |= (1u << d);
    }
    unsigned pack = (unsigned)lperm[0][p] | ((unsigned)lperm[1][p] << 6) |
                    ((unsigned)lperm[2][p] << 12) | (mask << 18);
    packg[(it * 32 + b) * 50 + p] = pack;
  }
}

// ============================================================================
// Chamfer eval core (verified R6 — bitwise identical d2/min/sum path).
// Scalar form (R5) — R6/R7's packed-fp32 variant cut issue but raised wall.
// ============================================================================
__device__ __forceinline__ float eval_pose_core(
    float p0, float p1, float p2, float p3, float p4, float p5,
    float s0, float s1, float s2, int tid, const float4* syv, float4* xsv,
    float* rowpart, float* red1, float* red2) {
  float Rm[3][3];
  compute_R(p0, p1, p2, Rm);
  float x0 = fmaf(Rm[0][2], s2, fmaf(Rm[0][1], s1, Rm[0][0] * s0)) + p3;
  float x1 = fmaf(Rm[1][2], s2, fmaf(Rm[1][1], s1, Rm[1][0] * s0)) + p4;
  float x2 = fmaf(Rm[2][2], s2, fmaf(Rm[2][1], s1, Rm[2][0] * s0)) + p5;
  float xn = x0 * x0 + x1 * x1 + x2 * x2;
  xsv[tid] = make_float4(x0, x1, x2, xn);
  __syncthreads();
  int rg = tid & 31, cq = tid >> 5;
  float4 xr0 = xsv[4 * rg + 0];
  float4 xr1 = xsv[4 * rg + 1];
  float4 xr2 = xsv[4 * rg + 2];
  float4 xr3 = xsv[4 * rg + 3];
  float racc0 = 3.402823466e38f, racc1 = 3.402823466e38f;
  float racc2 = 3.402823466e38f, racc3 = 3.402823466e38f;
  float cacc[32];
#pragma unroll
  for (int cj = 0; cj < 32; cj++) {
    float4 y = syv[(cq << 5) + cj];
    float cr0 = fmaf(xr0.z, y.z, fmaf(xr0.y, y.y, xr0.x * y.x));
    float d0 = (xr0.w + y.w) - 2.0f * cr0; d0 = fmaxf(d0, 0.0f);
    float cr1 = fmaf(xr1.z, y.z, fmaf(xr1.y, y.y, xr1.x * y.x));
    float d1 = (xr1.w + y.w) - 2.0f * cr1; d1 = fmaxf(d1, 0.0f);
    float cr2 = fmaf(xr2.z, y.z, fmaf(xr2.y, y.y, xr2.x * y.x));
    float d2_ = (xr2.w + y.w) - 2.0f * cr2; d2_ = fmaxf(d2_, 0.0f);
    float cr3 = fmaf(xr3.z, y.z, fmaf(xr3.y, y.y, xr3.x * y.x));
    float d3 = (xr3.w + y.w) - 2.0f * cr3; d3 = fmaxf(d3, 0.0f);
    racc0 = fminf(racc0, d0); racc1 = fminf(racc1, d1);
    racc2 = fminf(racc2, d2_); racc3 = fminf(racc3, d3);
    cacc[cj] = fminf(fminf(d0, d1), fminf(d2_, d3));
  }
  rowpart[cq * 128 + 4 * rg + 0] = racc0;
  rowpart[cq * 128 + 4 * rg + 1] = racc1;
  rowpart[cq * 128 + 4 * rg + 2] = racc2;
  rowpart[cq * 128 + 4 * rg + 3] = racc3;
#pragma unroll
  for (int m = 16; m >= 1; m >>= 1) {
    bool hi = (rg & m) != 0;
#pragma unroll
    for (int j = 0; j < m; j++) {
      float lo_v = cacc[j], hi_v = cacc[j + m];
      float mine = hi ? hi_v : lo_v;
      float send = hi ? lo_v : hi_v;
      float recv = __shfl_xor(send, m, 64);
      cacc[j] = fminf(mine, recv);
    }
  }
  float colmin = cacc[0];
  __syncthreads();
  float rv = rowpart[tid];
  rv = fminf(rv, rowpart[128 + tid]);
  rv = fminf(rv, rowpart[256 + tid]);
  rv = fminf(rv, rowpart[384 + tid]);
  red1[tid] = rv;
  red2[tid] = colmin;
  __syncthreads();
  int l = tid & 63;
  float v1 = red1[l] + red1[l + 64];
  float v2 = red2[l] + red2[l + 64];
#pragma unroll
  for (int m = 32; m >= 1; m >>= 1) {
    v1 += __shfl_xor(v1, m, 64);
    v2 += __shfl_xor(v2, m, 64);
  }
  return v1 * 0.0078125f + v2 * 0.0078125f;
}

// prio-wrapped eval: eval waves get issue priority over spin/publish waves
// on the same CU (the dependency cascade waits on eval, not on spins).
__device__ __forceinline__ float eval_pose_prio(
    float p0, float p1, float p2, float p3, float p4, float p5,
    float s0, float s1, float s2, int tid, const float4* syv, float4* xsv,
    float* rowpart, float* red1, float* red2) {
  __builtin_amdgcn_s_setprio(1);
  float f = eval_pose_core(p0, p1, p2, p3, p4, p5, s0, s1, s2, tid, syv, xsv,
                           rowpart, red1, red2);
  __builtin_amdgcn_s_setprio(0);
  return f;
}

// pop0 value for particle r, dim d of batch b (pure function)
__device__ __forceinline__ float pop0_val(int b, int r, int d) {
  if (r == 0) return 0.0f;
  U2 root = root_key();
  unsigned ridx = (unsigned)((b * 50 + r) * 3 + (d % 3));
  if (d < 3) {
    U2 k2 = split_key(root, 5, 2);
    return jax_uniform(k2, 4800, ridx, -ROTR, ROTR);
  }
  U2 k3 = split_key(root, 5, 3);
  return jax_uniform(k3, 4800, ridx, -1.0f, 1.0f);
}

// ============================================================================
// Persistent kernel (R5/R8): sentinel-word dataflow pipeline, tight spins,
// wave-phase priority (setprio 1 during eval, 0 during spin/publish).
//   estate[it][bp][8] = {E[0..5], F, pad}; sentinel-initialized by setupperm.
//   Write-once words => no ordering, no flags, no fences, no barriers.
// Residency by construction: __launch_bounds__(128,4) -> 8 blocks/CU,
// capacity 2048 >= grid 1600 -> all blocks resident, spins can't deadlock.
// ============================================================================
__global__ __launch_bounds__(128, 4) void de_loop_kernel(
    const float* __restrict__ srcb, const float* __restrict__ tgtb,
    const float* __restrict__ ynb, const unsigned* __restrict__ packg,
    float* __restrict__ estate, const float* __restrict__ source,
    float* __restrict__ out) {
  int blk = blockIdx.x;
  int b = blk / 50, p = blk % 50;
  int bp = blk;
  int tid = threadIdx.x;
  __shared__ float strial[8];
  __shared__ float pv4[4][6];
  __shared__ float4 syv[128];
  __shared__ float4 xsv[128];
  __shared__ float rowpart[512];
  __shared__ float red1[128];
  __shared__ float red2[128];
  __shared__ float fl[52];
  __shared__ float Rsh2[12];

  {
    float y0 = tgtb[(b * 128 + tid) * 3 + 0];
    float y1 = tgtb[(b * 128 + tid) * 3 + 1];
    float y2 = tgtb[(b * 128 + tid) * 3 + 2];
    syv[tid] = make_float4(y0, y1, y2, ynb[b * 128 + tid]);
  }
  float s0 = srcb[(b * 128 + tid) * 3 + 0];
  float s1 = srcb[(b * 128 + tid) * 3 + 1];
  float s2 = srcb[(b * 128 + tid) * 3 + 2];

  float own_f = 0.0f;    // replicated across all threads (uniform updates)
  float own_e = 0.0f;    // valid in threads tid<6: dimension tid of E_k

  unsigned pack_next = packg[(0 * 32 + b) * 50 + p];

  for (int it = 0; it < 30; it++) {
    unsigned pack = pack_next;
    if (it < 29) pack_next = packg[((it + 1) * 32 + b) * 50 + p];  // prefetch
    int i1 = (int)(pack & 63u);
    int i2 = (int)((pack >> 6) & 63u);
    int i3 = (int)((pack >> 12) & 63u);
    unsigned mask = (pack >> 18) & 63u;

    if (it == 0) {
      if (tid < 24) {
        int u = tid / 6, d = tid % 6;
        int rows[4] = {p, i1, i2, i3};
        pv4[u][d] = pop0_val(b, rows[u], d);
      }
      __syncthreads();
      float f0 = eval_pose_prio(pv4[0][0], pv4[0][1], pv4[0][2], pv4[0][3],
                                pv4[0][4], pv4[0][5],
                                s0, s1, s2, tid, syv, xsv, rowpart, red1, red2);
      if (tid < 6) {
        int d = tid;
        float mu = pv4[1][d] + 0.8f * (pv4[2][d] - pv4[3][d]);
        if (d < 3) mu = fminf(fmaxf(mu, -ROTR), ROTR);
        else       mu = fminf(fmaxf(mu, -1.0f), 1.0f);
        float pv = pv4[0][d];
        float tv = ((mask >> d) & 1u) ? mu : pv;
        strial[d] = tv;
      }
      __syncthreads();
      float tf0 = eval_pose_prio(strial[0], strial[1], strial[2], strial[3],
                                 strial[4], strial[5],
                                 s0, s1, s2, tid, syv, xsv, rowpart, red1, red2);
      bool imp = tf0 < f0;
      own_f = imp ? tf0 : f0;
      if (tid < 6) own_e = imp ? strial[tid] : pv4[0][tid];
    } else {
      // ---- fused poll+read of the 3 donors' dim-d words (tight spin,
      //      prio 0 — do not steal issue slots from eval waves) ----
      if (tid < 6) {
        int d = tid;
        const float* eb = &estate[((size_t)(it - 1) * 1600 + b * 50) * 8];
        const unsigned* pa = (const unsigned*)&eb[i1 * 8 + d];
        const unsigned* pb = (const unsigned*)&eb[i2 * 8 + d];
        const unsigned* pc = (const unsigned*)&eb[i3 * 8 + d];
        unsigned va = uload(pa), vb = uload(pb), vc = uload(pc);
        while (va == SENTINEL || vb == SENTINEL || vc == SENTINEL) {
          va = uload(pa); vb = uload(pb); vc = uload(pc);
        }
        float x1v = __uint_as_float(va);
        float x2v = __uint_as_float(vb);
        float x3v = __uint_as_float(vc);
        float mu = x1v + 0.8f * (x2v - x3v);
        if (d < 3) mu = fminf(fmaxf(mu, -ROTR), ROTR);
        else       mu = fminf(fmaxf(mu, -1.0f), 1.0f);
        float tv = ((mask >> d) & 1u) ? mu : own_e;
        strial[d] = tv;
      }
      __syncthreads();  // strial visible to both waves
      float tfv = eval_pose_prio(strial[0], strial[1], strial[2], strial[3],
                                 strial[4], strial[5],
                                 s0, s1, s2, tid, syv, xsv, rowpart, red1, red2);
      bool imp = tfv < own_f;
      own_f = imp ? tfv : own_f;
      if (tid < 6) own_e = imp ? strial[tid] : own_e;
    }

    // ---- publish slot it: fire-and-forget word stores (no drain/barrier) ---
    float* slot = &estate[((size_t)it * 1600 + bp) * 8];
    if (tid < 6)       gstore(&slot[tid], own_e);
    else if (tid == 6) gstore(&slot[6], own_f);
  }

  // ==== final selection (redundant per block -> no extra sync hop) ====
  if (tid < 50) {
    fl[tid] = poll_word(&estate[((size_t)29 * 1600 + b * 50 + tid) * 8 + 6]);
  }
  __syncthreads();
  if (tid == 0) {
    int bi = 0;
    float best = fl[0];
    for (int q = 1; q < 50; q++)
      if (fl[q] < best) { best = fl[q]; bi = q; }
    const float* ep = &estate[((size_t)29 * 1600 + b * 50 + bi) * 8];
    float v[6];
#pragma unroll
    for (int d = 0; d < 6; d++) v[d] = poll_word(&ep[d]);  // e/f unordered
    float R[3][3];
    compute_R(v[0], v[1], v[2], R);
#pragma unroll
    for (int i = 0; i < 3; i++)
#pragma unroll
      for (int j = 0; j < 3; j++) Rsh2[i * 3 + j] = R[i][j];
    Rsh2[9] = v[3]; Rsh2[10] = v[4]; Rsh2[11] = v[5];
    if (p == 0) {
#pragma unroll
      for (int e = 0; e < 9; e++) out[b * 9 + e] = Rsh2[e];
      out[288 + b * 3 + 0] = v[3];
      out[288 + b * 3 + 1] = v[4];
      out[288 + b * 3 + 2] = v[5];
    }
  }
  __syncthreads();

  // ==== aligned transform: batch b's 16384 points across its 50 blocks ====
  for (int k = p * 128 + tid; k < 16384; k += 6400) {
    size_t gid = (size_t)b * 16384 + k;
    float a0s = source[gid * 3 + 0];
    float a1s = source[gid * 3 + 1];
    float a2s = source[gid * 3 + 2];
    float a0 = fmaf(Rsh2[2], a2s, fmaf(Rsh2[1], a1s, Rsh2[0] * a0s)) + Rsh2[9];
    float a1 = fmaf(Rsh2[5], a2s, fmaf(Rsh2[4], a1s, Rsh2[3] * a0s)) + Rsh2[10];
    float a2 = fmaf(Rsh2[8], a2s, fmaf(Rsh2[7], a1s, Rsh2[6] * a0s)) + Rsh2[11];
    out[384 + gid * 3 + 0] = a0;
    out[384 + gid * 3 + 1] = a1;
    out[384 + gid * 3 + 2] = a2;
  }
}

// ============================================================================
extern "C" void kernel_launch(void* const* d_in, const int* in_sizes, int n_in,
                              void* d_out, int out_size, void* d_ws,
                              size_t ws_size, hipStream_t stream) {
  const float* source = (const float*)d_in[0];
  const float* target = (const float*)d_in[1];
  float* out = (float*)d_out;
  char* ws = (char*)d_ws;

  // --- workspace layout ---
  // persistent (live during de_loop):
  unsigned* packg    = (unsigned*)(ws + 0);         // 192000
  float* srcb        = (float*)(ws + 192000);       // 49152
  float* tgtb        = (float*)(ws + 241152);       // 49152
  float* ynb         = (float*)(ws + 290304);       // 16384
  int* idx           = (int*)(ws + 306688);         // 1024
  unsigned* hist     = (unsigned*)(ws + 307712);    // 4096
  unsigned* basep    = (unsigned*)(ws + 414208);    // 4096
  unsigned* cursor   = (unsigned*)(ws + 418304);    // 4096
  // sort scratch (dead after setup chain) overlaid by estate (stream-ordered):
  unsigned long long* sorted = (unsigned long long*)(ws + 422400);  // 524288
  unsigned* rank_all = (unsigned*)(ws + 946688);    // 262144
  unsigned* x1buf    = (unsigned*)(ws + 1208832);   // 131072
  float* estate      = (float*)(ws + 422400);       // 1536000 (overlay)

  hipMemsetAsync(hist, 0, 4096, stream);
  hist_kernel<<<256, 256, 0, stream>>>(hist);
  prefix_kernel<<<1, 256, 0, stream>>>(hist, basep, cursor);
  scatterb_kernel<<<256, 256, 0, stream>>>(cursor, sorted);
  rank_kernel<<<256, 256, 0, stream>>>(sorted, basep, hist, rank_all, x1buf);
  idx_kernel<<<128, 256, 0, stream>>>(rank_all, x1buf, idx);
  // setupperm also sentinel-inits estate (sort scratch dead from here)
  setupperm_kernel<<<992, 128, 0, stream>>>(source, target, idx, srcb, tgtb,
                                            ynb, packg, (unsigned*)estate);

  de_loop_kernel<<<1600, 128, 0, stream>>>(srcb, tgtb, ynb, packg, estate,
                                           source, out);
}